// Round 4
// baseline (518.733 us; speedup 1.0000x reference)
//
#include <hip/hip_runtime.h>
#include <hip/hip_bf16.h>
#include <stdint.h>

#define B_   64
#define L_   4096
#define H_   128
#define T_   64
#define C_   (L_/T_)        // 64 chunks per batch row
#define PADI 136            // bf16 row stride for inp tile

typedef __attribute__((ext_vector_type(8))) short short8;
typedef __attribute__((ext_vector_type(4))) float floatx4;

#define LOG2E 1.44269504088896340736f

__device__ __forceinline__ unsigned short f2bf(float f){
    unsigned int u = __float_as_uint(f);
    u += 0x7FFFu + ((u >> 16) & 1u);      // RNE
    return (unsigned short)(u >> 16);
}
__device__ __forceinline__ float bf2f(unsigned short s){
    return __uint_as_float(((unsigned int)s) << 16);
}

// K0: W^T bf16 prep (dense [n][k]) + zero the look-back flags.
__global__ void prep_w(const float* __restrict__ Wz, const float* __restrict__ Wh,
                       unsigned short* __restrict__ WzT, unsigned short* __restrict__ WhT,
                       int* __restrict__ flags){
    int tid = threadIdx.x;
    if (blockIdx.x < 2){
        const float* W = blockIdx.x ? Wh : Wz;
        unsigned short* WT = blockIdx.x ? WhT : WzT;
        for (int it = 0; it < 64; ++it){
            int idx = it*256 + tid;           // idx = n*128 + k
            int n = idx >> 7, k = idx & 127;
            WT[idx] = f2bf(W[k*H_ + n]);
        }
    } else {
        for (int i = 0; i < 16; ++i) flags[i*256 + tid] = 0;   // 4096 flags
    }
}

// Fused: inp + 2 GEMMs + gates (LDS) + local scan + decoupled look-back +
// carried rewrite-scan + fused Wg readout. One dispatch, no ab HBM traffic.
// Block order chunk-major: bid = cc*B_ + bb, so a chunk's predecessors have
// strictly smaller blockIdx (monotone HW dispatch => no deadlock).
__global__ __launch_bounds__(256, 4)
void fused_mingru(const float* __restrict__ x,
                  const float* __restrict__ Wp, const float* __restrict__ bp,
                  const float* __restrict__ bz, const float* __restrict__ bh,
                  const float* __restrict__ Wg, const float* __restrict__ bg,
                  const unsigned short* __restrict__ WzT,
                  const unsigned short* __restrict__ WhT,
                  float* __restrict__ aggA, float* __restrict__ aggH,
                  float* __restrict__ inclH, int* __restrict__ flags,
                  float* __restrict__ preds)
{
    __shared__ __align__(16) unsigned short s_ab[H_*H_];   // 32 KB (inp tile overlays)
    __shared__ float s_bz[H_], s_bh[H_], s_wg[H_];
    unsigned short* inp_lds = s_ab;                        // 64*136 ushorts

    const int bid = blockIdx.x;
    const int bb  = bid & (B_-1);        // chunk-major: bid = cc*64 + bb
    const int cc  = bid >> 6;
    const int t0g = cc * T_;
    const int tid = threadIdx.x;
    const int wv = tid >> 6, lane = tid & 63, quad = lane >> 4, l15 = lane & 15;

    if (tid < H_){ s_bz[tid] = bz[tid]; s_bh[tid] = bh[tid]; s_wg[tid] = Wg[tid]; }

    // ---- inp = x @ Wp + bp -> bf16 LDS (A layout [t][k]) ----
    #pragma unroll
    for (int it = 0; it < 4; ++it){
        int idx = tid + it*256;
        int t = idx >> 4, h0 = (idx & 15) * 8;
        const float* xr = x + ((size_t)bb*L_ + t0g + t)*3;
        float x0 = xr[0], x1 = xr[1], x2 = xr[2];
        short8 pk;
        #pragma unroll
        for (int m = 0; m < 8; ++m){
            int hh = h0 + m;
            float v = bp[hh];
            v = fmaf(x0, Wp[hh],      v);
            v = fmaf(x1, Wp[H_+hh],   v);
            v = fmaf(x2, Wp[2*H_+hh], v);
            pk[m] = (short)f2bf(v);
        }
        *(short8*)&inp_lds[t*PADI + h0] = pk;
    }
    __syncthreads();

    const int ct0 = wv*2;

    // ---- GEMM1: Sz = inp @ Wz^T (B-frags from global, L2-hot) ----
    floatx4 accz[4][2];
    #pragma unroll
    for (int r = 0; r < 4; ++r)
        #pragma unroll
        for (int c = 0; c < 2; ++c) accz[r][c] = (floatx4){0.f,0.f,0.f,0.f};
    #pragma unroll
    for (int kk = 0; kk < 4; ++kk){
        short8 af[4], bfr[2];
        #pragma unroll
        for (int r = 0; r < 4; ++r)
            af[r] = *(const short8*)&inp_lds[(r*16 + l15)*PADI + kk*32 + quad*8];
        #pragma unroll
        for (int c = 0; c < 2; ++c)
            bfr[c] = *(const short8*)&WzT[((ct0+c)*16 + l15)*H_ + kk*32 + quad*8];
        #pragma unroll
        for (int r = 0; r < 4; ++r)
            #pragma unroll
            for (int c = 0; c < 2; ++c)
                accz[r][c] = __builtin_amdgcn_mfma_f32_16x16x32_bf16(af[r], bfr[c], accz[r][c], 0, 0, 0);
    }

    // a = 1 - sigmoid(sz) = sigmoid(-sz); quantize to bf16 now (frees accz)
    unsigned int a2[4][2][2];
    #pragma unroll
    for (int r = 0; r < 4; ++r){
        #pragma unroll
        for (int c = 0; c < 2; ++c){
            int col = (ct0+c)*16 + l15;
            float vbz = s_bz[col];
            unsigned short q[4];
            #pragma unroll
            for (int e = 0; e < 4; ++e){
                float szb = accz[r][c][e] + vbz;
                float a = __builtin_amdgcn_rcpf(1.0f + __builtin_amdgcn_exp2f(szb * LOG2E));
                q[e] = f2bf(a);
            }
            a2[r][c][0] = (unsigned int)q[0] | ((unsigned int)q[1] << 16);
            a2[r][c][1] = (unsigned int)q[2] | ((unsigned int)q[3] << 16);
        }
    }

    // ---- GEMM2: Sh = inp @ Wh^T ----
    floatx4 acch[4][2];
    #pragma unroll
    for (int r = 0; r < 4; ++r)
        #pragma unroll
        for (int c = 0; c < 2; ++c) acch[r][c] = (floatx4){0.f,0.f,0.f,0.f};
    #pragma unroll
    for (int kk = 0; kk < 4; ++kk){
        short8 af[4], bfr[2];
        #pragma unroll
        for (int r = 0; r < 4; ++r)
            af[r] = *(const short8*)&inp_lds[(r*16 + l15)*PADI + kk*32 + quad*8];
        #pragma unroll
        for (int c = 0; c < 2; ++c)
            bfr[c] = *(const short8*)&WhT[((ct0+c)*16 + l15)*H_ + kk*32 + quad*8];
        #pragma unroll
        for (int r = 0; r < 4; ++r)
            #pragma unroll
            for (int c = 0; c < 2; ++c)
                acch[r][c] = __builtin_amdgcn_mfma_f32_16x16x32_bf16(af[r], bfr[c], acch[r][c], 0, 0, 0);
    }
    __syncthreads();   // inp reads done before ab overlay

    // ---- epilogue: b = (1-a)*tanh(sh); swizzled (a,b) b128 chunks in LDS ----
    #pragma unroll
    for (int r = 0; r < 4; ++r){
        #pragma unroll
        for (int c = 0; c < 2; ++c){
            int col = (ct0+c)*16 + l15;
            float vbh = s_bh[col];
            short8 pk;
            #pragma unroll
            for (int e = 0; e < 4; ++e){
                unsigned short abf = (unsigned short)(a2[r][c][e>>1] >> ((e & 1)*16));
                float a = bf2f(abf);
                float z = 1.0f - a;
                float shb = acch[r][c][e] + vbh;
                float e2 = __builtin_amdgcn_exp2f(2.0f*LOG2E*fabsf(shb));
                float tt = 1.0f - 2.0f*__builtin_amdgcn_rcpf(e2 + 1.0f);
                float bt = z * copysignf(tt, shb);
                pk[2*e]   = (short)abf;
                pk[2*e+1] = (short)f2bf(bt);
            }
            int ch = (r*4 + quad) ^ l15;
            *(short8*)&s_ab[col*H_ + ch*8] = pk;
        }
    }
    __syncthreads();

    // ---- local scan: A = prod a, hloc = scan from 0 ----
    float A = 1.0f, hloc = 0.0f;
    if (tid < H_){
        #pragma unroll
        for (int t4 = 0; t4 < 16; ++t4){
            short8 pr = *(const short8*)&s_ab[tid*H_ + ((t4 ^ (tid & 15)) << 3)];
            #pragma unroll
            for (int e = 0; e < 4; ++e){
                float aa = bf2f((unsigned short)pr[2*e]);
                float bv = bf2f((unsigned short)pr[2*e+1]);
                A *= aa;
                hloc = fmaf(aa, hloc, bv);
            }
        }
        aggA[(size_t)bid*H_ + tid] = A;
        aggH[(size_t)bid*H_ + tid] = hloc;
    }
    __syncthreads();                       // drain agg stores (all waves)
    if (tid == 0)
        __hip_atomic_store(&flags[bid], 1, __ATOMIC_RELEASE, __HIP_MEMORY_SCOPE_AGENT);

    // ---- decoupled look-back: compose carry c from predecessors ----
    float c = 0.0f;
    if (tid < H_){
        float accA = 1.0f;
        int p = cc - 1;
        while (p >= 0){
            int pb = p*B_ + bb;
            int f;
            while (1){
                f = __hip_atomic_load(&flags[pb], __ATOMIC_RELAXED, __HIP_MEMORY_SCOPE_AGENT);
                if (f == 1 || f == 2) break;
                __builtin_amdgcn_s_sleep(1);
            }
            (void)__hip_atomic_load(&flags[pb], __ATOMIC_ACQUIRE, __HIP_MEMORY_SCOPE_AGENT);
            if (f == 2){
                c = fmaf(accA, inclH[(size_t)pb*H_ + tid], c);
                break;
            } else {
                c = fmaf(accA, aggH[(size_t)pb*H_ + tid], c);
                accA *= aggA[(size_t)pb*H_ + tid];
                --p;
            }
        }
        inclH[(size_t)bid*H_ + tid] = fmaf(A, c, hloc);
    }
    __syncthreads();                       // drain inclH stores
    if (tid == 0)
        __hip_atomic_store(&flags[bid], 2, __ATOMIC_RELEASE, __HIP_MEMORY_SCOPE_AGENT);

    // ---- carried rewrite-scan: a-slots <- h_prev * wg ----
    if (tid < H_){
        float h = c;
        float wgv = s_wg[tid];
        #pragma unroll
        for (int t4 = 0; t4 < 16; ++t4){
            int base = tid*H_ + ((t4 ^ (tid & 15)) << 3);
            short8 pr = *(const short8*)&s_ab[base];
            #pragma unroll
            for (int e = 0; e < 4; ++e){
                float aa = bf2f((unsigned short)pr[2*e]);
                float bv = bf2f((unsigned short)pr[2*e+1]);
                s_ab[base + 2*e] = f2bf(h * wgv);
                h = fmaf(aa, h, bv);
            }
        }
    }
    __syncthreads();

    // ---- readout: preds[t] = sum_col (h_prev*wg)[col][t] + bg ----
    {
        int t = tid >> 2, q = tid & 3;
        float s = 0.0f;
        #pragma unroll
        for (int j = 0; j < 32; ++j){
            int col = q*32 + j;
            s += bf2f(s_ab[col*H_ + (((t >> 2) ^ (col & 15)) << 3) + (t & 3)*2]);
        }
        s += __shfl_xor(s, 1, 64);
        s += __shfl_xor(s, 2, 64);
        if (q == 0) preds[(size_t)bb*L_ + t0g + t] = s + bg[0];
    }
}

extern "C" void kernel_launch(void* const* d_in, const int* in_sizes, int n_in,
                              void* d_out, int out_size, void* d_ws, size_t ws_size,
                              hipStream_t stream){
    const float* x  = (const float*)d_in[0];
    const float* Wp = (const float*)d_in[1];
    const float* bp = (const float*)d_in[2];
    const float* Wz = (const float*)d_in[3];
    const float* bz = (const float*)d_in[4];
    const float* Wh = (const float*)d_in[5];
    const float* bh = (const float*)d_in[6];
    const float* Wg = (const float*)d_in[7];
    const float* bg = (const float*)d_in[8];
    float* preds = (float*)d_out;

    uint8_t* w8 = (uint8_t*)d_ws;
    unsigned short* WzT = (unsigned short*)(w8);
    unsigned short* WhT = (unsigned short*)(w8 + 32768);
    const size_t NCH = (size_t)B_ * C_;                  // 4096
    float* aggA  = (float*)(w8 + 65536);
    float* aggH  = (float*)(w8 + 65536 + 4u*NCH*H_);
    float* inclH = (float*)(w8 + 65536 + 8u*NCH*H_);
    int*   flags = (int*)  (w8 + 65536 + 12u*NCH*H_);

    hipLaunchKernelGGL(prep_w, dim3(3), dim3(256), 0, stream, Wz, Wh, WzT, WhT, flags);
    hipLaunchKernelGGL(fused_mingru, dim3(B_*C_), dim3(256), 0, stream,
                       x, Wp, bp, bz, bh, Wg, bg, WzT, WhT,
                       aggA, aggH, inclH, flags, preds);
}

// Round 5
// 247.286 us; speedup vs baseline: 2.0977x; 2.0977x over previous
//
#include <hip/hip_runtime.h>
#include <hip/hip_bf16.h>
#include <stdint.h>

#define B_   64
#define L_   4096
#define H_   128
#define T_   64
#define C_   (L_/T_)        // 64 chunks per batch row
#define BH_  (B_*H_)        // 8192
#define PADI 136            // bf16 row stride for inp tile

typedef __attribute__((ext_vector_type(8))) short short8;
typedef __attribute__((ext_vector_type(4))) float floatx4;

#define LOG2E 1.44269504088896340736f

__device__ __forceinline__ unsigned short f2bf(float f){
    unsigned int u = __float_as_uint(f);
    u += 0x7FFFu + ((u >> 16) & 1u);      // RNE
    return (unsigned short)(u >> 16);
}
__device__ __forceinline__ float bf2f(unsigned short s){
    return __uint_as_float(((unsigned int)s) << 16);
}

// K0: W^T bf16 prep (dense [n][k]); both passes read the SAME bf16 weights,
// so pass-2's recomputed `a` is bit-identical to pass-1's.
__global__ void prep_w(const float* __restrict__ Wz, const float* __restrict__ Wh,
                       unsigned short* __restrict__ WzT, unsigned short* __restrict__ WhT){
    const float* W = blockIdx.x ? Wh : Wz;
    unsigned short* WT = blockIdx.x ? WhT : WzT;
    int tid = threadIdx.x;
    for (int it = 0; it < 64; ++it){
        int idx = it*256 + tid;           // idx = n*128 + k
        int n = idx >> 7, k = idx & 127;
        WT[idx] = f2bf(W[k*H_ + n]);
    }
}

// ab LDS layout: row col (0..127) of 256B; 16B chunk t4 at position t4^(col&15).
// Pair (a,b) for t = t4*4+e at ushorts [chunk*8 + 2e, +1].

// Pass 1: inp + 2 GEMMs + gates + merged local scan/rewrite + local readout.
// Outputs: aggA/aggH (chunk aggregates) and sloc[t] = dot(hloc_{t-1}, wg).
__global__ __launch_bounds__(256, 4)
void gates_agg(const float* __restrict__ x,
               const float* __restrict__ Wp, const float* __restrict__ bp,
               const float* __restrict__ bz, const float* __restrict__ bh,
               const float* __restrict__ Wg,
               const unsigned short* __restrict__ WzT,
               const unsigned short* __restrict__ WhT,
               float* __restrict__ aggA, float* __restrict__ aggH,
               float* __restrict__ sloc)
{
    __shared__ __align__(16) unsigned short s_ab[H_*H_];   // 32 KB (inp tile overlays)
    __shared__ float s_bz[H_], s_bh[H_], s_wg[H_];
    unsigned short* inp_lds = s_ab;

    const int bid = blockIdx.x;
    const int bb  = bid / C_;
    const int cc  = bid % C_;
    const int t0g = cc * T_;
    const int tid = threadIdx.x;
    const int wv = tid >> 6, lane = tid & 63, quad = lane >> 4, l15 = lane & 15;

    if (tid < H_){ s_bz[tid] = bz[tid]; s_bh[tid] = bh[tid]; s_wg[tid] = Wg[tid]; }

    // ---- inp = x @ Wp + bp -> bf16 LDS (A layout [t][k]) ----
    #pragma unroll
    for (int it = 0; it < 4; ++it){
        int idx = tid + it*256;
        int t = idx >> 4, h0 = (idx & 15) * 8;
        const float* xr = x + ((size_t)bb*L_ + t0g + t)*3;
        float x0 = xr[0], x1 = xr[1], x2 = xr[2];
        short8 pk;
        #pragma unroll
        for (int m = 0; m < 8; ++m){
            int hh = h0 + m;
            float v = bp[hh];
            v = fmaf(x0, Wp[hh],      v);
            v = fmaf(x1, Wp[H_+hh],   v);
            v = fmaf(x2, Wp[2*H_+hh], v);
            pk[m] = (short)f2bf(v);
        }
        *(short8*)&inp_lds[t*PADI + h0] = pk;
    }
    __syncthreads();

    const int ct0 = wv*2;

    // ---- GEMM1: Sz = inp @ Wz^T (B-frags from global, L2-hot) ----
    floatx4 accz[4][2];
    #pragma unroll
    for (int r = 0; r < 4; ++r)
        #pragma unroll
        for (int c = 0; c < 2; ++c) accz[r][c] = (floatx4){0.f,0.f,0.f,0.f};
    #pragma unroll
    for (int kk = 0; kk < 4; ++kk){
        short8 af[4], bfr[2];
        #pragma unroll
        for (int r = 0; r < 4; ++r)
            af[r] = *(const short8*)&inp_lds[(r*16 + l15)*PADI + kk*32 + quad*8];
        #pragma unroll
        for (int c = 0; c < 2; ++c)
            bfr[c] = *(const short8*)&WzT[((ct0+c)*16 + l15)*H_ + kk*32 + quad*8];
        #pragma unroll
        for (int r = 0; r < 4; ++r)
            #pragma unroll
            for (int c = 0; c < 2; ++c)
                accz[r][c] = __builtin_amdgcn_mfma_f32_16x16x32_bf16(af[r], bfr[c], accz[r][c], 0, 0, 0);
    }

    // a = 1 - sigmoid(sz); quantize to bf16 now (frees accz)
    unsigned int a2[4][2][2];
    #pragma unroll
    for (int r = 0; r < 4; ++r){
        #pragma unroll
        for (int c = 0; c < 2; ++c){
            int col = (ct0+c)*16 + l15;
            float vbz = s_bz[col];
            unsigned short q[4];
            #pragma unroll
            for (int e = 0; e < 4; ++e){
                float szb = accz[r][c][e] + vbz;
                float a = __builtin_amdgcn_rcpf(1.0f + __builtin_amdgcn_exp2f(szb * LOG2E));
                q[e] = f2bf(a);
            }
            a2[r][c][0] = (unsigned int)q[0] | ((unsigned int)q[1] << 16);
            a2[r][c][1] = (unsigned int)q[2] | ((unsigned int)q[3] << 16);
        }
    }

    // ---- GEMM2: Sh = inp @ Wh^T ----
    floatx4 acch[4][2];
    #pragma unroll
    for (int r = 0; r < 4; ++r)
        #pragma unroll
        for (int c = 0; c < 2; ++c) acch[r][c] = (floatx4){0.f,0.f,0.f,0.f};
    #pragma unroll
    for (int kk = 0; kk < 4; ++kk){
        short8 af[4], bfr[2];
        #pragma unroll
        for (int r = 0; r < 4; ++r)
            af[r] = *(const short8*)&inp_lds[(r*16 + l15)*PADI + kk*32 + quad*8];
        #pragma unroll
        for (int c = 0; c < 2; ++c)
            bfr[c] = *(const short8*)&WhT[((ct0+c)*16 + l15)*H_ + kk*32 + quad*8];
        #pragma unroll
        for (int r = 0; r < 4; ++r)
            #pragma unroll
            for (int c = 0; c < 2; ++c)
                acch[r][c] = __builtin_amdgcn_mfma_f32_16x16x32_bf16(af[r], bfr[c], acch[r][c], 0, 0, 0);
    }
    __syncthreads();   // inp reads done before ab overlay

    // ---- epilogue: b = (1-a)*tanh(sh); swizzled (a,b) b128 chunks in LDS ----
    #pragma unroll
    for (int r = 0; r < 4; ++r){
        #pragma unroll
        for (int c = 0; c < 2; ++c){
            int col = (ct0+c)*16 + l15;
            float vbh = s_bh[col];
            short8 pk;
            #pragma unroll
            for (int e = 0; e < 4; ++e){
                unsigned short abf = (unsigned short)(a2[r][c][e>>1] >> ((e & 1)*16));
                float a = bf2f(abf);
                float z = 1.0f - a;
                float shb = acch[r][c][e] + vbh;
                float e2 = __builtin_amdgcn_exp2f(2.0f*LOG2E*fabsf(shb));
                float tt = 1.0f - 2.0f*__builtin_amdgcn_rcpf(e2 + 1.0f);
                float bt = z * copysignf(tt, shb);
                pk[2*e]   = (short)abf;
                pk[2*e+1] = (short)f2bf(bt);
            }
            int ch = (r*4 + quad) ^ l15;
            *(short8*)&s_ab[col*H_ + ch*8] = pk;
        }
    }
    __syncthreads();

    // ---- merged local scan (c=0): agg + rewrite a-slot <- hloc_{t-1}*wg ----
    if (tid < H_){
        float A = 1.0f, h = 0.0f;
        float wgv = s_wg[tid];
        #pragma unroll
        for (int t4 = 0; t4 < 16; ++t4){
            int base = tid*H_ + ((t4 ^ (tid & 15)) << 3);
            short8 pr = *(const short8*)&s_ab[base];
            #pragma unroll
            for (int e = 0; e < 4; ++e){
                float aa = bf2f((unsigned short)pr[2*e]);
                float bv = bf2f((unsigned short)pr[2*e+1]);
                s_ab[base + 2*e] = f2bf(h * wgv);   // hloc_{t-1} * wg
                A *= aa;
                h = fmaf(aa, h, bv);
            }
        }
        aggA[cc*BH_ + bb*H_ + tid] = A;
        aggH[cc*BH_ + bb*H_ + tid] = h;
    }
    __syncthreads();

    // ---- local readout: sloc[t] = sum_col (hloc_{t-1}*wg)[col][t] ----
    {
        int t = tid >> 2, q = tid & 3;
        float s = 0.0f;
        #pragma unroll
        for (int j = 0; j < 32; ++j){
            int col = q*32 + j;
            s += bf2f(s_ab[col*H_ + (((t >> 2) ^ (col & 15)) << 3) + (t & 3)*2]);
        }
        s += __shfl_xor(s, 1, 64);
        s += __shfl_xor(s, 2, 64);
        if (q == 0) sloc[(size_t)bid*T_ + t] = s;
    }
}

// Pass 2: recompute a (GEMM1 + sigmoid only), self-compose carry from the
// L2-hot aggregates, cumprod-rewrite g = A_{t-1}*c*wg, add sloc + bg -> preds.
__global__ __launch_bounds__(256, 4)
void apply_carry(const float* __restrict__ x,
                 const float* __restrict__ Wp, const float* __restrict__ bp,
                 const float* __restrict__ bz,
                 const float* __restrict__ Wg, const float* __restrict__ bg,
                 const unsigned short* __restrict__ WzT,
                 const float* __restrict__ aggA, const float* __restrict__ aggH,
                 const float* __restrict__ sloc,
                 float* __restrict__ preds)
{
    __shared__ __align__(16) unsigned short s_ab[H_*H_];
    __shared__ float s_bz[H_], s_wg[H_];
    unsigned short* inp_lds = s_ab;

    const int bid = blockIdx.x;
    const int bb  = bid / C_;
    const int cc  = bid % C_;
    const int t0g = cc * T_;
    const int tid = threadIdx.x;
    const int wv = tid >> 6, lane = tid & 63, quad = lane >> 4, l15 = lane & 15;

    if (tid < H_){ s_bz[tid] = bz[tid]; s_wg[tid] = Wg[tid]; }

    // ---- inp (identical to pass 1) ----
    #pragma unroll
    for (int it = 0; it < 4; ++it){
        int idx = tid + it*256;
        int t = idx >> 4, h0 = (idx & 15) * 8;
        const float* xr = x + ((size_t)bb*L_ + t0g + t)*3;
        float x0 = xr[0], x1 = xr[1], x2 = xr[2];
        short8 pk;
        #pragma unroll
        for (int m = 0; m < 8; ++m){
            int hh = h0 + m;
            float v = bp[hh];
            v = fmaf(x0, Wp[hh],      v);
            v = fmaf(x1, Wp[H_+hh],   v);
            v = fmaf(x2, Wp[2*H_+hh], v);
            pk[m] = (short)f2bf(v);
        }
        *(short8*)&inp_lds[t*PADI + h0] = pk;
    }
    __syncthreads();

    const int ct0 = wv*2;

    // ---- GEMM1 only ----
    floatx4 accz[4][2];
    #pragma unroll
    for (int r = 0; r < 4; ++r)
        #pragma unroll
        for (int c = 0; c < 2; ++c) accz[r][c] = (floatx4){0.f,0.f,0.f,0.f};
    #pragma unroll
    for (int kk = 0; kk < 4; ++kk){
        short8 af[4], bfr[2];
        #pragma unroll
        for (int r = 0; r < 4; ++r)
            af[r] = *(const short8*)&inp_lds[(r*16 + l15)*PADI + kk*32 + quad*8];
        #pragma unroll
        for (int c = 0; c < 2; ++c)
            bfr[c] = *(const short8*)&WzT[((ct0+c)*16 + l15)*H_ + kk*32 + quad*8];
        #pragma unroll
        for (int r = 0; r < 4; ++r)
            #pragma unroll
            for (int c = 0; c < 2; ++c)
                accz[r][c] = __builtin_amdgcn_mfma_f32_16x16x32_bf16(af[r], bfr[c], accz[r][c], 0, 0, 0);
    }

    // a values (bit-identical quantization to pass 1)
    unsigned int a2[4][2][2];
    #pragma unroll
    for (int r = 0; r < 4; ++r){
        #pragma unroll
        for (int c = 0; c < 2; ++c){
            int col = (ct0+c)*16 + l15;
            float vbz = s_bz[col];
            unsigned short q[4];
            #pragma unroll
            for (int e = 0; e < 4; ++e){
                float szb = accz[r][c][e] + vbz;
                float a = __builtin_amdgcn_rcpf(1.0f + __builtin_amdgcn_exp2f(szb * LOG2E));
                q[e] = f2bf(a);
            }
            a2[r][c][0] = (unsigned int)q[0] | ((unsigned int)q[1] << 16);
            a2[r][c][1] = (unsigned int)q[2] | ((unsigned int)q[3] << 16);
        }
    }
    __syncthreads();   // inp reads done before a overlay

    // ---- write a into pair layout (b-slot zero) ----
    #pragma unroll
    for (int r = 0; r < 4; ++r){
        #pragma unroll
        for (int c = 0; c < 2; ++c){
            int col = (ct0+c)*16 + l15;
            short8 pk;
            #pragma unroll
            for (int e = 0; e < 4; ++e){
                pk[2*e]   = (short)(unsigned short)(a2[r][c][e>>1] >> ((e & 1)*16));
                pk[2*e+1] = 0;
            }
            int ch = (r*4 + quad) ^ l15;
            *(short8*)&s_ab[col*H_ + ch*8] = pk;
        }
    }

    // ---- compose carry c for this chunk from aggregates (L2-hot, 4 MB) ----
    float cval = 0.0f;
    if (tid < H_){
        for (int ch = 0; ch < cc; ++ch){
            float ga = aggA[ch*BH_ + bb*H_ + tid];
            float gh = aggH[ch*BH_ + bb*H_ + tid];
            cval = fmaf(ga, cval, gh);
        }
    }
    __syncthreads();

    // ---- cumprod rewrite: a-slot <- A_{t-1}*c*wg ----
    if (tid < H_){
        float u = cval * s_wg[tid];
        #pragma unroll
        for (int t4 = 0; t4 < 16; ++t4){
            int base = tid*H_ + ((t4 ^ (tid & 15)) << 3);
            short8 pr = *(const short8*)&s_ab[base];
            #pragma unroll
            for (int e = 0; e < 4; ++e){
                float aa = bf2f((unsigned short)pr[2*e]);
                s_ab[base + 2*e] = f2bf(u);
                u *= aa;
            }
        }
    }
    __syncthreads();

    // ---- readout: preds = sum_col g + sloc + bg ----
    {
        int t = tid >> 2, q = tid & 3;
        float s = 0.0f;
        #pragma unroll
        for (int j = 0; j < 32; ++j){
            int col = q*32 + j;
            s += bf2f(s_ab[col*H_ + (((t >> 2) ^ (col & 15)) << 3) + (t & 3)*2]);
        }
        s += __shfl_xor(s, 1, 64);
        s += __shfl_xor(s, 2, 64);
        if (q == 0)
            preds[(size_t)bb*L_ + t0g + t] = s + sloc[(size_t)bid*T_ + t] + bg[0];
    }
}

extern "C" void kernel_launch(void* const* d_in, const int* in_sizes, int n_in,
                              void* d_out, int out_size, void* d_ws, size_t ws_size,
                              hipStream_t stream){
    const float* x  = (const float*)d_in[0];
    const float* Wp = (const float*)d_in[1];
    const float* bp = (const float*)d_in[2];
    const float* Wz = (const float*)d_in[3];
    const float* bz = (const float*)d_in[4];
    const float* Wh = (const float*)d_in[5];
    const float* bh = (const float*)d_in[6];
    const float* Wg = (const float*)d_in[7];
    const float* bg = (const float*)d_in[8];
    float* preds = (float*)d_out;

    uint8_t* w8 = (uint8_t*)d_ws;
    unsigned short* WzT = (unsigned short*)(w8);
    unsigned short* WhT = (unsigned short*)(w8 + 32768);
    float* aggA = (float*)(w8 + 65536);                       // 2 MB
    float* aggH = (float*)(w8 + 65536 + 4u*BH_*C_);           // 2 MB
    float* sloc = (float*)(w8 + 65536 + 8u*BH_*C_);           // 1 MB

    hipLaunchKernelGGL(prep_w, dim3(2), dim3(256), 0, stream, Wz, Wh, WzT, WhT);
    hipLaunchKernelGGL(gates_agg, dim3(B_*C_), dim3(256), 0, stream,
                       x, Wp, bp, bz, bh, Wg, WzT, WhT, aggA, aggH, sloc);
    hipLaunchKernelGGL(apply_carry, dim3(B_*C_), dim3(256), 0, stream,
                       x, Wp, bp, bz, Wg, bg, WzT, aggA, aggH, sloc, preds);
}

// Round 6
// 171.885 us; speedup vs baseline: 3.0179x; 1.4387x over previous
//
#include <hip/hip_runtime.h>
#include <hip/hip_bf16.h>
#include <stdint.h>

#define B_   64
#define L_   4096
#define H_   128
#define T_   64
#define C_   (L_/T_)        // 64 chunks per batch row
#define BH_  (B_*H_)        // 8192
#define PADI 136            // bf16 row stride for inp tile
#define PWS  72             // ushort stride of Pw rows (144 B, 16B-aligned)

typedef __attribute__((ext_vector_type(8))) short short8;
typedef __attribute__((ext_vector_type(4))) short short4v;
typedef __attribute__((ext_vector_type(4))) float floatx4;

#define LOG2E 1.44269504088896340736f

__device__ __forceinline__ unsigned short f2bf(float f){
    unsigned int u = __float_as_uint(f);
    u += 0x7FFFu + ((u >> 16) & 1u);      // RNE
    return (unsigned short)(u >> 16);
}
__device__ __forceinline__ float bf2f(unsigned short s){
    return __uint_as_float(((unsigned int)s) << 16);
}

// K0: W^T bf16 prep (dense [n][k]); 32 blocks for latency spread.
__global__ void prep_w(const float* __restrict__ Wz, const float* __restrict__ Wh,
                       unsigned short* __restrict__ WzT, unsigned short* __restrict__ WhT){
    int b = blockIdx.x;
    const float* W = (b < 16) ? Wz : Wh;
    unsigned short* WT = (b < 16) ? WzT : WhT;
    int b16 = b & 15, tid = threadIdx.x;
    #pragma unroll
    for (int it = 0; it < 4; ++it){
        int idx = b16*1024 + it*256 + tid;    // idx = n*128 + k
        int n = idx >> 7, k = idx & 127;
        WT[idx] = f2bf(W[k*H_ + n]);
    }
}

// ab LDS layout: row col (0..127) of 256B; 16B chunk t4 at position t4^(col&15).
// Pair (a,b) for t = t4*4+e at ushorts [chunk*8 + 2e, +1].

// Pass 1: inp + 2 GEMMs + gates + merged scan (agg + hloc*wg rewrite + Pw pack)
// + local readout sloc + coalesced Pw copy-out.
__global__ __launch_bounds__(256, 3)
void gates_agg(const float* __restrict__ x,
               const float* __restrict__ Wp, const float* __restrict__ bp,
               const float* __restrict__ bz, const float* __restrict__ bh,
               const float* __restrict__ Wg,
               const unsigned short* __restrict__ WzT,
               const unsigned short* __restrict__ WhT,
               float* __restrict__ aggA, float* __restrict__ aggH,
               float* __restrict__ sloc, unsigned short* __restrict__ pw_g)
{
    __shared__ __align__(16) unsigned short s_ab[H_*H_];    // 32 KB (inp overlays)
    __shared__ __align__(16) unsigned short s_pw[H_*PWS];   // 18 KB Pw staging
    __shared__ float s_bz[H_], s_bh[H_], s_wg[H_];
    unsigned short* inp_lds = s_ab;

    const int bid = blockIdx.x;
    const int bb  = bid / C_;
    const int cc  = bid % C_;
    const int t0g = cc * T_;
    const int tid = threadIdx.x;
    const int wv = tid >> 6, lane = tid & 63, quad = lane >> 4, l15 = lane & 15;

    if (tid < H_){ s_bz[tid] = bz[tid]; s_bh[tid] = bh[tid]; s_wg[tid] = Wg[tid]; }

    // ---- inp = x @ Wp + bp -> bf16 LDS (A layout [t][k]) ----
    #pragma unroll
    for (int it = 0; it < 4; ++it){
        int idx = tid + it*256;
        int t = idx >> 4, h0 = (idx & 15) * 8;
        const float* xr = x + ((size_t)bb*L_ + t0g + t)*3;
        float x0 = xr[0], x1 = xr[1], x2 = xr[2];
        short8 pk;
        #pragma unroll
        for (int m = 0; m < 8; ++m){
            int hh = h0 + m;
            float v = bp[hh];
            v = fmaf(x0, Wp[hh],      v);
            v = fmaf(x1, Wp[H_+hh],   v);
            v = fmaf(x2, Wp[2*H_+hh], v);
            pk[m] = (short)f2bf(v);
        }
        *(short8*)&inp_lds[t*PADI + h0] = pk;
    }
    __syncthreads();

    const int ct0 = wv*2;

    // ---- GEMM1: Sz = inp @ Wz^T (B-frags from global, L2-hot) ----
    floatx4 accz[4][2];
    #pragma unroll
    for (int r = 0; r < 4; ++r)
        #pragma unroll
        for (int c = 0; c < 2; ++c) accz[r][c] = (floatx4){0.f,0.f,0.f,0.f};
    #pragma unroll
    for (int kk = 0; kk < 4; ++kk){
        short8 af[4], bfr[2];
        #pragma unroll
        for (int r = 0; r < 4; ++r)
            af[r] = *(const short8*)&inp_lds[(r*16 + l15)*PADI + kk*32 + quad*8];
        #pragma unroll
        for (int c = 0; c < 2; ++c)
            bfr[c] = *(const short8*)&WzT[((ct0+c)*16 + l15)*H_ + kk*32 + quad*8];
        #pragma unroll
        for (int r = 0; r < 4; ++r)
            #pragma unroll
            for (int c = 0; c < 2; ++c)
                accz[r][c] = __builtin_amdgcn_mfma_f32_16x16x32_bf16(af[r], bfr[c], accz[r][c], 0, 0, 0);
    }

    // a = 1 - sigmoid(sz); quantize to bf16 now (frees accz)
    unsigned int a2[4][2][2];
    #pragma unroll
    for (int r = 0; r < 4; ++r){
        #pragma unroll
        for (int c = 0; c < 2; ++c){
            int col = (ct0+c)*16 + l15;
            float vbz = s_bz[col];
            unsigned short q[4];
            #pragma unroll
            for (int e = 0; e < 4; ++e){
                float szb = accz[r][c][e] + vbz;
                float a = __builtin_amdgcn_rcpf(1.0f + __builtin_amdgcn_exp2f(szb * LOG2E));
                q[e] = f2bf(a);
            }
            a2[r][c][0] = (unsigned int)q[0] | ((unsigned int)q[1] << 16);
            a2[r][c][1] = (unsigned int)q[2] | ((unsigned int)q[3] << 16);
        }
    }

    // ---- GEMM2: Sh = inp @ Wh^T ----
    floatx4 acch[4][2];
    #pragma unroll
    for (int r = 0; r < 4; ++r)
        #pragma unroll
        for (int c = 0; c < 2; ++c) acch[r][c] = (floatx4){0.f,0.f,0.f,0.f};
    #pragma unroll
    for (int kk = 0; kk < 4; ++kk){
        short8 af[4], bfr[2];
        #pragma unroll
        for (int r = 0; r < 4; ++r)
            af[r] = *(const short8*)&inp_lds[(r*16 + l15)*PADI + kk*32 + quad*8];
        #pragma unroll
        for (int c = 0; c < 2; ++c)
            bfr[c] = *(const short8*)&WhT[((ct0+c)*16 + l15)*H_ + kk*32 + quad*8];
        #pragma unroll
        for (int r = 0; r < 4; ++r)
            #pragma unroll
            for (int c = 0; c < 2; ++c)
                acch[r][c] = __builtin_amdgcn_mfma_f32_16x16x32_bf16(af[r], bfr[c], acch[r][c], 0, 0, 0);
    }
    __syncthreads();   // inp reads done before ab overlay

    // ---- epilogue: b = (1-a)*tanh(sh); swizzled (a,b) b128 chunks in LDS ----
    #pragma unroll
    for (int r = 0; r < 4; ++r){
        #pragma unroll
        for (int c = 0; c < 2; ++c){
            int col = (ct0+c)*16 + l15;
            float vbh = s_bh[col];
            short8 pk;
            #pragma unroll
            for (int e = 0; e < 4; ++e){
                unsigned short abf = (unsigned short)(a2[r][c][e>>1] >> ((e & 1)*16));
                float a = bf2f(abf);
                float z = 1.0f - a;
                float shb = acch[r][c][e] + vbh;
                float e2 = __builtin_amdgcn_exp2f(2.0f*LOG2E*fabsf(shb));
                float tt = 1.0f - 2.0f*__builtin_amdgcn_rcpf(e2 + 1.0f);
                float bt = z * copysignf(tt, shb);
                pk[2*e]   = (short)abf;
                pk[2*e+1] = (short)f2bf(bt);
            }
            int ch = (r*4 + quad) ^ l15;
            *(short8*)&s_ab[col*H_ + ch*8] = pk;
        }
    }
    __syncthreads();

    // ---- merged scan: agg + a-slot <- hloc_{t-1}*wg + Pw = P(t)*wg pack ----
    if (tid < H_){
        float A = 1.0f, h = 0.0f;
        float wgv = s_wg[tid];
        #pragma unroll
        for (int t4 = 0; t4 < 16; ++t4){
            int base = tid*H_ + ((t4 ^ (tid & 15)) << 3);
            short8 pr = *(const short8*)&s_ab[base];
            short4v pw4;
            #pragma unroll
            for (int e = 0; e < 4; ++e){
                float aa = bf2f((unsigned short)pr[2*e]);
                float bv = bf2f((unsigned short)pr[2*e+1]);
                s_ab[base + 2*e] = f2bf(h * wgv);     // hloc_{t-1} * wg
                pw4[e] = (short)f2bf(A * wgv);        // P(t)*wg (A before update)
                A *= aa;
                h = fmaf(aa, h, bv);
            }
            *(short4v*)&s_pw[tid*PWS + t4*4] = pw4;
        }
        aggA[cc*BH_ + bb*H_ + tid] = A;
        aggH[cc*BH_ + bb*H_ + tid] = h;
    }
    __syncthreads();

    // ---- local readout: sloc[t] = sum_col (hloc_{t-1}*wg)[col][t] ----
    {
        int t = tid >> 2, q = tid & 3;
        float s = 0.0f;
        #pragma unroll
        for (int j = 0; j < 32; ++j){
            int col = q*32 + j;
            s += bf2f(s_ab[col*H_ + (((t >> 2) ^ (col & 15)) << 3) + (t & 3)*2]);
        }
        s += __shfl_xor(s, 1, 64);
        s += __shfl_xor(s, 2, 64);
        if (q == 0) sloc[(size_t)bid*T_ + t] = s;
    }

    // ---- Pw copy-out (coalesced b128) ----
    {
        unsigned short* dst = pw_g + (size_t)bid * (H_*PWS);
        #pragma unroll
        for (int i = 0; i < 4; ++i){
            int idx = tid + i*256;
            *(short8*)&dst[idx*8] = *(const short8*)&s_pw[idx*8];
        }
        if (tid < 128){
            int idx = 1024 + tid;
            *(short8*)&dst[idx*8] = *(const short8*)&s_pw[idx*8];
        }
    }
}

// Pass 2 (light): branchless-unrolled carry compose + u = c*Pw (fp32 LDS) +
// column-sum readout + sloc + bg. No GEMM, no transcendentals.
__global__ __launch_bounds__(256, 4)
void apply2(const unsigned short* __restrict__ pw_g,
            const float* __restrict__ aggA, const float* __restrict__ aggH,
            const float* __restrict__ sloc, const float* __restrict__ bg,
            float* __restrict__ preds)
{
    __shared__ float s_u[H_*65];     // 33280 B, stride 65 (bank-spread)
    const int bid = blockIdx.x;
    const int bb  = bid / C_;
    const int cc  = bid % C_;
    const int t0g = cc * T_;
    const int tid = threadIdx.x;

    if (tid < H_){
        // carry for this chunk: fixed-64 predicated loop -> full prefetch
        float cval = 0.0f;
        #pragma unroll
        for (int ch = 0; ch < C_; ++ch){
            float ga = aggA[ch*BH_ + bb*H_ + tid];
            float gh = aggH[ch*BH_ + bb*H_ + tid];
            bool in = ch < cc;
            cval = fmaf(in ? ga : 1.0f, cval, in ? gh : 0.0f);
        }
        // u[t] = c * Pw[t]
        const unsigned short* row = pw_g + (size_t)bid*(H_*PWS) + tid*PWS;
        #pragma unroll
        for (int i = 0; i < 8; ++i){
            short8 pw8 = *(const short8*)&row[i*8];
            #pragma unroll
            for (int e = 0; e < 8; ++e)
                s_u[tid*65 + i*8 + e] = cval * bf2f((unsigned short)pw8[e]);
        }
    }
    __syncthreads();

    int t = tid >> 2, q = tid & 3;
    float s = 0.0f;
    #pragma unroll
    for (int j = 0; j < 32; ++j){
        int col = q*32 + j;
        s += s_u[col*65 + t];
    }
    s += __shfl_xor(s, 1, 64);
    s += __shfl_xor(s, 2, 64);
    if (q == 0)
        preds[(size_t)bb*L_ + t0g + t] = s + sloc[(size_t)bid*T_ + t] + bg[0];
}

extern "C" void kernel_launch(void* const* d_in, const int* in_sizes, int n_in,
                              void* d_out, int out_size, void* d_ws, size_t ws_size,
                              hipStream_t stream){
    const float* x  = (const float*)d_in[0];
    const float* Wp = (const float*)d_in[1];
    const float* bp = (const float*)d_in[2];
    const float* Wz = (const float*)d_in[3];
    const float* bz = (const float*)d_in[4];
    const float* Wh = (const float*)d_in[5];
    const float* bh = (const float*)d_in[6];
    const float* Wg = (const float*)d_in[7];
    const float* bg = (const float*)d_in[8];
    float* preds = (float*)d_out;

    uint8_t* w8 = (uint8_t*)d_ws;
    unsigned short* WzT = (unsigned short*)(w8);
    unsigned short* WhT = (unsigned short*)(w8 + 32768);
    float* aggA = (float*)(w8 + 65536);                       // 2 MB
    float* aggH = (float*)(w8 + 65536 + 4u*BH_*C_);           // 2 MB
    float* sloc = (float*)(w8 + 65536 + 8u*BH_*C_);           // 1 MB
    unsigned short* pw_g = (unsigned short*)(w8 + 65536 + 12u*BH_*C_);  // 75.5 MB

    hipLaunchKernelGGL(prep_w, dim3(32), dim3(256), 0, stream, Wz, Wh, WzT, WhT);
    hipLaunchKernelGGL(gates_agg, dim3(B_*C_), dim3(256), 0, stream,
                       x, Wp, bp, bz, bh, Wg, WzT, WhT, aggA, aggH, sloc, pw_g);
    hipLaunchKernelGGL(apply2, dim3(B_*C_), dim3(256), 0, stream,
                       pw_g, aggA, aggH, sloc, bg, preds);
}

// Round 7
// 160.883 us; speedup vs baseline: 3.2243x; 1.0684x over previous
//
#include <hip/hip_runtime.h>
#include <hip/hip_bf16.h>
#include <stdint.h>

#define B_   64
#define L_   4096
#define H_   128
#define T_   64
#define C_   (L_/T_)        // 64 chunks per batch row
#define BH_  (B_*H_)        // 8192
#define PADI 136            // bf16 row stride for inp tile

typedef __attribute__((ext_vector_type(8))) short short8;
typedef __attribute__((ext_vector_type(4))) short short4v;
typedef __attribute__((ext_vector_type(4))) float floatx4;

#define LOG2E 1.44269504088896340736f

__device__ __forceinline__ unsigned short f2bf(float f){
    unsigned int u = __float_as_uint(f);
    u += 0x7FFFu + ((u >> 16) & 1u);      // RNE
    return (unsigned short)(u >> 16);
}
__device__ __forceinline__ float bf2f(unsigned short s){
    return __uint_as_float(((unsigned int)s) << 16);
}

// K0: W^T bf16 prep (dense [n][k]); 32 blocks.
__global__ void prep_w(const float* __restrict__ Wz, const float* __restrict__ Wh,
                       unsigned short* __restrict__ WzT, unsigned short* __restrict__ WhT){
    int b = blockIdx.x;
    const float* W = (b < 16) ? Wz : Wh;
    unsigned short* WT = (b < 16) ? WzT : WhT;
    int b16 = b & 15, tid = threadIdx.x;
    #pragma unroll
    for (int it = 0; it < 4; ++it){
        int idx = b16*1024 + it*256 + tid;    // idx = n*128 + k
        int n = idx >> 7, k = idx & 127;
        WT[idx] = f2bf(W[k*H_ + n]);
    }
}

// ab LDS layout: row col (0..127) of 256B; 16B chunk t4 at position t4^(col&15).
// Pair (a,b) for t = t4*4+e at ushorts [chunk*8 + 2e, +1]. After the scan the
// pair is overwritten in place with (hw, pw) = (hloc_{t-1}*wg, P(t)*wg).

// Pass 1: inp + 2 GEMMs + combined gate epilogue + in-place scan
// (agg + hw/pw) + conflict-free sloc reduction + register->global pw dump.
__global__ __launch_bounds__(256, 4)
void gates_agg(const float* __restrict__ x,
               const float* __restrict__ Wp, const float* __restrict__ bp,
               const float* __restrict__ bz, const float* __restrict__ bh,
               const float* __restrict__ Wg,
               const unsigned short* __restrict__ WzT,
               const unsigned short* __restrict__ WhT,
               float* __restrict__ aggA, float* __restrict__ aggH,
               float* __restrict__ sloc, unsigned short* __restrict__ pw_g)
{
    __shared__ __align__(16) unsigned short s_ab[H_*H_];    // 32 KB (inp overlays)
    __shared__ float s_bz[H_], s_bh[H_], s_wg[H_];
    __shared__ float s_part[256];
    unsigned short* inp_lds = s_ab;

    const int bid = blockIdx.x;
    const int bb  = bid / C_;
    const int cc  = bid % C_;
    const int t0g = cc * T_;
    const int tid = threadIdx.x;
    const int wv = tid >> 6, lane = tid & 63, quad = lane >> 4, l15 = lane & 15;

    if (tid < H_){ s_bz[tid] = bz[tid]; s_bh[tid] = bh[tid]; s_wg[tid] = Wg[tid]; }

    // ---- inp = x @ Wp + bp -> bf16 LDS (A layout [t][k]) ----
    #pragma unroll
    for (int it = 0; it < 4; ++it){
        int idx = tid + it*256;
        int t = idx >> 4, h0 = (idx & 15) * 8;
        const float* xr = x + ((size_t)bb*L_ + t0g + t)*3;
        float x0 = xr[0], x1 = xr[1], x2 = xr[2];
        short8 pk;
        #pragma unroll
        for (int m = 0; m < 8; ++m){
            int hh = h0 + m;
            float v = bp[hh];
            v = fmaf(x0, Wp[hh],      v);
            v = fmaf(x1, Wp[H_+hh],   v);
            v = fmaf(x2, Wp[2*H_+hh], v);
            pk[m] = (short)f2bf(v);
        }
        *(short8*)&inp_lds[t*PADI + h0] = pk;
    }
    __syncthreads();

    const int ct0 = wv*2;

    // ---- GEMM1: Sz = inp @ Wz^T (B-frags from global, L2-hot) ----
    floatx4 accz[4][2];
    #pragma unroll
    for (int r = 0; r < 4; ++r)
        #pragma unroll
        for (int c = 0; c < 2; ++c) accz[r][c] = (floatx4){0.f,0.f,0.f,0.f};
    #pragma unroll
    for (int kk = 0; kk < 4; ++kk){
        short8 af[4], bfr[2];
        #pragma unroll
        for (int r = 0; r < 4; ++r)
            af[r] = *(const short8*)&inp_lds[(r*16 + l15)*PADI + kk*32 + quad*8];
        #pragma unroll
        for (int c = 0; c < 2; ++c)
            bfr[c] = *(const short8*)&WzT[((ct0+c)*16 + l15)*H_ + kk*32 + quad*8];
        #pragma unroll
        for (int r = 0; r < 4; ++r)
            #pragma unroll
            for (int c = 0; c < 2; ++c)
                accz[r][c] = __builtin_amdgcn_mfma_f32_16x16x32_bf16(af[r], bfr[c], accz[r][c], 0, 0, 0);
    }

    // ---- GEMM2: Sh = inp @ Wh^T ----
    floatx4 acch[4][2];
    #pragma unroll
    for (int r = 0; r < 4; ++r)
        #pragma unroll
        for (int c = 0; c < 2; ++c) acch[r][c] = (floatx4){0.f,0.f,0.f,0.f};
    #pragma unroll
    for (int kk = 0; kk < 4; ++kk){
        short8 af[4], bfr[2];
        #pragma unroll
        for (int r = 0; r < 4; ++r)
            af[r] = *(const short8*)&inp_lds[(r*16 + l15)*PADI + kk*32 + quad*8];
        #pragma unroll
        for (int c = 0; c < 2; ++c)
            bfr[c] = *(const short8*)&WhT[((ct0+c)*16 + l15)*H_ + kk*32 + quad*8];
        #pragma unroll
        for (int r = 0; r < 4; ++r)
            #pragma unroll
            for (int c = 0; c < 2; ++c)
                acch[r][c] = __builtin_amdgcn_mfma_f32_16x16x32_bf16(af[r], bfr[c], acch[r][c], 0, 0, 0);
    }
    __syncthreads();   // inp reads done before ab overlay

    // ---- combined epilogue: a = sigmoid(-sz), b = (1-a)*tanh(sh) ----
    #pragma unroll
    for (int r = 0; r < 4; ++r){
        #pragma unroll
        for (int c = 0; c < 2; ++c){
            int col = (ct0+c)*16 + l15;
            float vbz = s_bz[col], vbh = s_bh[col];
            short8 pk;
            #pragma unroll
            for (int e = 0; e < 4; ++e){
                float szb = accz[r][c][e] + vbz;
                float a = __builtin_amdgcn_rcpf(1.0f + __builtin_amdgcn_exp2f(szb * LOG2E));
                unsigned short abf = f2bf(a);
                float af_ = bf2f(abf);
                float z = 1.0f - af_;
                float shb = acch[r][c][e] + vbh;
                float e2 = __builtin_amdgcn_exp2f(2.0f*LOG2E*fabsf(shb));
                float tt = 1.0f - 2.0f*__builtin_amdgcn_rcpf(e2 + 1.0f);
                float bt = z * copysignf(tt, shb);
                pk[2*e]   = (short)abf;
                pk[2*e+1] = (short)f2bf(bt);
            }
            int ch = (r*4 + quad) ^ l15;
            *(short8*)&s_ab[col*H_ + ch*8] = pk;
        }
    }
    __syncthreads();

    // ---- in-place scan: (a,b) -> (hw,pw); agg out; pw regs -> global ----
    if (tid < H_){
        float A = 1.0f, h = 0.0f;
        float wgv = s_wg[tid];
        unsigned short* pwdst = pw_g + (size_t)bid*(T_*H_) + tid*T_;
        #pragma unroll
        for (int t4 = 0; t4 < 16; ++t4){
            int base = tid*H_ + ((t4 ^ (tid & 15)) << 3);
            short8 pr = *(const short8*)&s_ab[base];
            short8 wb;
            short4v pq;
            #pragma unroll
            for (int e = 0; e < 4; ++e){
                float aa = bf2f((unsigned short)pr[2*e]);
                float bv = bf2f((unsigned short)pr[2*e+1]);
                unsigned short hwq = f2bf(h * wgv);
                unsigned short pwq = f2bf(A * wgv);
                wb[2*e]   = (short)hwq;
                wb[2*e+1] = (short)pwq;
                pq[e]     = (short)pwq;
                A *= aa;
                h = fmaf(aa, h, bv);
            }
            *(short8*)&s_ab[base] = wb;            // in-place, same banks as read
            *(short4v*)&pwdst[t4*4] = pq;          // reg -> global (L2 merges)
        }
        aggA[cc*BH_ + bb*H_ + tid] = A;
        aggH[cc*BH_ + bb*H_ + tid] = h;
    }
    __syncthreads();

    // ---- sloc reduction, conflict-free (lane index = t) ----
    {
        int t = tid & 63, w4 = tid >> 6;
        int t4 = t >> 2, e2 = (t & 3)*2;
        float s = 0.0f;
        #pragma unroll
        for (int j = 0; j < 32; ++j){
            int col = w4*32 + j;
            s += bf2f(s_ab[col*H_ + ((t4 ^ (col & 15)) << 3) + e2]);
        }
        s_part[w4*64 + t] = s;
    }
    __syncthreads();
    if (tid < 64)
        sloc[(size_t)bid*T_ + tid] =
            s_part[tid] + s_part[64+tid] + s_part[128+tid] + s_part[192+tid];
}

// Pass 2 (light): LDS-staged pw + unrolled carry compose + conflict-free
// column-sum readout. No GEMM, no transcendentals.
__global__ __launch_bounds__(256, 4)
void apply2(const unsigned short* __restrict__ pw_g,
            const float* __restrict__ aggA, const float* __restrict__ aggH,
            const float* __restrict__ sloc, const float* __restrict__ bg,
            float* __restrict__ preds)
{
    __shared__ __align__(16) unsigned short s_pw[T_*H_];   // 16 KB [col][t]
    __shared__ float s_c[H_];
    __shared__ float s_part[256];
    const int bid = blockIdx.x;
    const int bb  = bid / C_;
    const int cc  = bid % C_;
    const int t0g = cc * T_;
    const int tid = threadIdx.x;
    const int wv = tid >> 6, lane = tid & 63;

    // stage pw tile (coalesced direct-to-LDS), overlapped with carry compose
    {
        const char* src = (const char*)(pw_g + (size_t)bid*(T_*H_));
        char* dst = (char*)s_pw;
        #pragma unroll
        for (int i = 0; i < 4; ++i){
            int off = (wv*4 + i)*1024;
            __builtin_amdgcn_global_load_lds(
                (const __attribute__((address_space(1))) unsigned int*)(src + off + lane*16),
                (__attribute__((address_space(3))) unsigned int*)(dst + off), 16, 0, 0);
        }
    }
    if (tid < H_){
        float cval = 0.0f;
        #pragma unroll
        for (int ch = 0; ch < C_; ++ch){
            float ga = aggA[ch*BH_ + bb*H_ + tid];
            float gh = aggH[ch*BH_ + bb*H_ + tid];
            bool in = ch < cc;
            cval = fmaf(in ? ga : 1.0f, cval, in ? gh : 0.0f);
        }
        s_c[tid] = cval;
    }
    __syncthreads();

    // conflict-free readout: lane index = t, each wave sums 32 cols
    {
        int t = tid & 63, w4 = tid >> 6;
        float s = 0.0f;
        #pragma unroll
        for (int j = 0; j < 32; ++j){
            int col = w4*32 + j;
            s += s_c[col] * bf2f(s_pw[col*T_ + t]);
        }
        s_part[w4*64 + t] = s;
    }
    __syncthreads();
    if (tid < 64){
        float s = s_part[tid] + s_part[64+tid] + s_part[128+tid] + s_part[192+tid];
        preds[(size_t)bb*L_ + t0g + tid] = s + sloc[(size_t)bid*T_ + tid] + bg[0];
    }
}

extern "C" void kernel_launch(void* const* d_in, const int* in_sizes, int n_in,
                              void* d_out, int out_size, void* d_ws, size_t ws_size,
                              hipStream_t stream){
    const float* x  = (const float*)d_in[0];
    const float* Wp = (const float*)d_in[1];
    const float* bp = (const float*)d_in[2];
    const float* Wz = (const float*)d_in[3];
    const float* bz = (const float*)d_in[4];
    const float* Wh = (const float*)d_in[5];
    const float* bh = (const float*)d_in[6];
    const float* Wg = (const float*)d_in[7];
    const float* bg = (const float*)d_in[8];
    float* preds = (float*)d_out;

    uint8_t* w8 = (uint8_t*)d_ws;
    unsigned short* WzT = (unsigned short*)(w8);
    unsigned short* WhT = (unsigned short*)(w8 + 32768);
    float* aggA = (float*)(w8 + 65536);                       // 2 MB
    float* aggH = (float*)(w8 + 65536 + 4u*BH_*C_);           // 2 MB
    float* sloc = (float*)(w8 + 65536 + 8u*BH_*C_);           // 1 MB
    unsigned short* pw_g = (unsigned short*)(w8 + 65536 + 12u*BH_*C_);  // 64 MB

    hipLaunchKernelGGL(prep_w, dim3(32), dim3(256), 0, stream, Wz, Wh, WzT, WhT);
    hipLaunchKernelGGL(gates_agg, dim3(B_*C_), dim3(256), 0, stream,
                       x, Wp, bp, bz, bh, Wg, WzT, WhT, aggA, aggH, sloc, pw_g);
    hipLaunchKernelGGL(apply2, dim3(B_*C_), dim3(256), 0, stream,
                       pw_g, aggA, aggH, sloc, bg, preds);
}

// Round 8
// 159.876 us; speedup vs baseline: 3.2446x; 1.0063x over previous
//
#include <hip/hip_runtime.h>
#include <hip/hip_bf16.h>
#include <stdint.h>

#define B_   64
#define L_   4096
#define H_   128
#define T_   64
#define C_   (L_/T_)        // 64 chunks per batch row
#define BH_  (B_*H_)        // 8192
#define PADI 136            // bf16 row stride for inp tile

typedef __attribute__((ext_vector_type(8))) short short8;
typedef __attribute__((ext_vector_type(4))) short short4v;
typedef __attribute__((ext_vector_type(4))) float floatx4;

#define LOG2E 1.44269504088896340736f

__device__ __forceinline__ unsigned short f2bf(float f){
    unsigned int u = __float_as_uint(f);
    u += 0x7FFFu + ((u >> 16) & 1u);      // RNE
    return (unsigned short)(u >> 16);
}
__device__ __forceinline__ float bf2f(unsigned short s){
    return __uint_as_float(((unsigned int)s) << 16);
}

// K0: W^T bf16 prep (dense [n][k]); 32 blocks.
__global__ void prep_w(const float* __restrict__ Wz, const float* __restrict__ Wh,
                       unsigned short* __restrict__ WzT, unsigned short* __restrict__ WhT){
    int b = blockIdx.x;
    const float* W = (b < 16) ? Wz : Wh;
    unsigned short* WT = (b < 16) ? WzT : WhT;
    int b16 = b & 15, tid = threadIdx.x;
    #pragma unroll
    for (int it = 0; it < 4; ++it){
        int idx = b16*1024 + it*256 + tid;    // idx = n*128 + k
        int n = idx >> 7, k = idx & 127;
        WT[idx] = f2bf(W[k*H_ + n]);
    }
}

// ab LDS layout: row col (0..127) of 256B; 16B chunk t4 at position t4^(col&15).
// Pair (a,b) for t = t4*4+e at ushorts [chunk*8 + 2e, +1]. After the scan the
// pair holds (hw, pw) = (hloc_{t-1}*wg, P(t)*wg) in the same slots.

// Pass 1: inp + 2 GEMMs + combined gate epilogue + LDS-only in-place scan +
// coalesced pw dump + conflict-free sloc reduction.
__global__ __launch_bounds__(256, 4)
void gates_agg(const float* __restrict__ x,
               const float* __restrict__ Wp, const float* __restrict__ bp,
               const float* __restrict__ bz, const float* __restrict__ bh,
               const float* __restrict__ Wg,
               const unsigned short* __restrict__ WzT,
               const unsigned short* __restrict__ WhT,
               float* __restrict__ aggA, float* __restrict__ aggH,
               float* __restrict__ sloc, unsigned short* __restrict__ pw_g)
{
    __shared__ __align__(16) unsigned short s_ab[H_*H_];    // 32 KB (inp overlays)
    __shared__ float s_bz[H_], s_bh[H_], s_wg[H_];
    __shared__ float s_part[256];
    unsigned short* inp_lds = s_ab;

    const int bid = blockIdx.x;
    const int bb  = bid / C_;
    const int cc  = bid % C_;
    const int t0g = cc * T_;
    const int tid = threadIdx.x;
    const int wv = tid >> 6, lane = tid & 63, quad = lane >> 4, l15 = lane & 15;

    if (tid < H_){ s_bz[tid] = bz[tid]; s_bh[tid] = bh[tid]; s_wg[tid] = Wg[tid]; }

    // ---- inp = x @ Wp + bp -> bf16 LDS (A layout [t][k]); Wp/bp hoisted ----
    {
        const int h0 = (tid & 15) * 8;         // iteration-invariant
        float w0[8], w1[8], w2[8], b0[8];
        #pragma unroll
        for (int m = 0; m < 8; ++m){
            w0[m] = Wp[h0+m]; w1[m] = Wp[H_+h0+m]; w2[m] = Wp[2*H_+h0+m];
            b0[m] = bp[h0+m];
        }
        #pragma unroll
        for (int it = 0; it < 4; ++it){
            int t = (tid >> 4) + it*16;
            const float* xr = x + ((size_t)bb*L_ + t0g + t)*3;
            float x0 = xr[0], x1 = xr[1], x2 = xr[2];
            short8 pk;
            #pragma unroll
            for (int m = 0; m < 8; ++m){
                float v = b0[m];
                v = fmaf(x0, w0[m], v);
                v = fmaf(x1, w1[m], v);
                v = fmaf(x2, w2[m], v);
                pk[m] = (short)f2bf(v);
            }
            *(short8*)&inp_lds[t*PADI + h0] = pk;
        }
    }
    __syncthreads();

    const int ct0 = wv*2;

    // ---- GEMM1: Sz = inp @ Wz^T (B-frags from global, L2-hot) ----
    floatx4 accz[4][2];
    #pragma unroll
    for (int r = 0; r < 4; ++r)
        #pragma unroll
        for (int c = 0; c < 2; ++c) accz[r][c] = (floatx4){0.f,0.f,0.f,0.f};
    #pragma unroll
    for (int kk = 0; kk < 4; ++kk){
        short8 af[4], bfr[2];
        #pragma unroll
        for (int r = 0; r < 4; ++r)
            af[r] = *(const short8*)&inp_lds[(r*16 + l15)*PADI + kk*32 + quad*8];
        #pragma unroll
        for (int c = 0; c < 2; ++c)
            bfr[c] = *(const short8*)&WzT[((ct0+c)*16 + l15)*H_ + kk*32 + quad*8];
        #pragma unroll
        for (int r = 0; r < 4; ++r)
            #pragma unroll
            for (int c = 0; c < 2; ++c)
                accz[r][c] = __builtin_amdgcn_mfma_f32_16x16x32_bf16(af[r], bfr[c], accz[r][c], 0, 0, 0);
    }

    // ---- GEMM2: Sh = inp @ Wh^T ----
    floatx4 acch[4][2];
    #pragma unroll
    for (int r = 0; r < 4; ++r)
        #pragma unroll
        for (int c = 0; c < 2; ++c) acch[r][c] = (floatx4){0.f,0.f,0.f,0.f};
    #pragma unroll
    for (int kk = 0; kk < 4; ++kk){
        short8 af[4], bfr[2];
        #pragma unroll
        for (int r = 0; r < 4; ++r)
            af[r] = *(const short8*)&inp_lds[(r*16 + l15)*PADI + kk*32 + quad*8];
        #pragma unroll
        for (int c = 0; c < 2; ++c)
            bfr[c] = *(const short8*)&WhT[((ct0+c)*16 + l15)*H_ + kk*32 + quad*8];
        #pragma unroll
        for (int r = 0; r < 4; ++r)
            #pragma unroll
            for (int c = 0; c < 2; ++c)
                acch[r][c] = __builtin_amdgcn_mfma_f32_16x16x32_bf16(af[r], bfr[c], acch[r][c], 0, 0, 0);
    }
    __syncthreads();   // inp reads done before ab overlay

    // ---- combined epilogue: a = sigmoid(-sz), b = (1-a)*tanh(sh) ----
    #pragma unroll
    for (int r = 0; r < 4; ++r){
        #pragma unroll
        for (int c = 0; c < 2; ++c){
            int col = (ct0+c)*16 + l15;
            float vbz = s_bz[col], vbh = s_bh[col];
            short8 pk;
            #pragma unroll
            for (int e = 0; e < 4; ++e){
                float szb = accz[r][c][e] + vbz;
                float a = __builtin_amdgcn_rcpf(1.0f + __builtin_amdgcn_exp2f(szb * LOG2E));
                unsigned short abf = f2bf(a);
                float af_ = bf2f(abf);
                float z = 1.0f - af_;
                float shb = acch[r][c][e] + vbh;
                float e2 = __builtin_amdgcn_exp2f(2.0f*LOG2E*fabsf(shb));
                float tt = 1.0f - 2.0f*__builtin_amdgcn_rcpf(e2 + 1.0f);
                float bt = z * copysignf(tt, shb);
                pk[2*e]   = (short)abf;
                pk[2*e+1] = (short)f2bf(bt);
            }
            int ch = (r*4 + quad) ^ l15;
            *(short8*)&s_ab[col*H_ + ch*8] = pk;
        }
    }
    __syncthreads();

    // ---- LDS-only in-place scan: (a,b) -> (hw,pw); agg out ----
    if (tid < H_){
        float A = 1.0f, h = 0.0f;
        float wgv = s_wg[tid];
        #pragma unroll
        for (int t4 = 0; t4 < 16; ++t4){
            int base = tid*H_ + ((t4 ^ (tid & 15)) << 3);
            short8 pr = *(const short8*)&s_ab[base];
            short8 wb;
            #pragma unroll
            for (int e = 0; e < 4; ++e){
                float aa = bf2f((unsigned short)pr[2*e]);
                float bv = bf2f((unsigned short)pr[2*e+1]);
                wb[2*e]   = (short)f2bf(h * wgv);   // hloc_{t-1} * wg
                wb[2*e+1] = (short)f2bf(A * wgv);   // P(t) * wg
                A *= aa;
                h = fmaf(aa, h, bv);
            }
            *(short8*)&s_ab[base] = wb;             // in-place, same banks
        }
        aggA[cc*BH_ + bb*H_ + tid] = A;
        aggH[cc*BH_ + bb*H_ + tid] = h;
    }
    __syncthreads();

    // ---- coalesced pw dump: deinterleave to [col][t], all 256 threads ----
    {
        unsigned short* dst = pw_g + (size_t)bid*(T_*H_);
        #pragma unroll
        for (int i = 0; i < 8; ++i){
            int idx = i*256 + tid;                 // (col, t4)
            int col = idx >> 4, t4 = idx & 15;
            short8 pr = *(const short8*)&s_ab[col*H_ + ((t4 ^ (col & 15)) << 3)];
            short4v pw4;
            pw4[0] = pr[1]; pw4[1] = pr[3]; pw4[2] = pr[5]; pw4[3] = pr[7];
            *(short4v*)&dst[col*T_ + t4*4] = pw4;  // consecutive 8B per thread
        }
    }

    // ---- sloc reduction, conflict-free (lane index = t) ----
    {
        int t = tid & 63, w4 = tid >> 6;
        int t4 = t >> 2, e2 = (t & 3)*2;
        float s = 0.0f;
        #pragma unroll
        for (int j = 0; j < 32; ++j){
            int col = w4*32 + j;
            s += bf2f(s_ab[col*H_ + ((t4 ^ (col & 15)) << 3) + e2]);
        }
        s_part[w4*64 + t] = s;
    }
    __syncthreads();
    if (tid < 64)
        sloc[(size_t)bid*T_ + tid] =
            s_part[tid] + s_part[64+tid] + s_part[128+tid] + s_part[192+tid];
}

// Pass 2 (light): unrolled carry compose + per-wave coalesced pw reads +
// conflict-free column-sum readout. No GEMM, no transcendentals, 2.5 KB LDS.
__global__ __launch_bounds__(256, 4)
void apply2(const unsigned short* __restrict__ pw_g,
            const float* __restrict__ aggA, const float* __restrict__ aggH,
            const float* __restrict__ sloc, const float* __restrict__ bg,
            float* __restrict__ preds)
{
    __shared__ float s_c[H_];
    __shared__ float s_part[256];
    const int bid = blockIdx.x;
    const int bb  = bid / C_;
    const int cc  = bid % C_;
    const int t0g = cc * T_;
    const int tid = threadIdx.x;

    if (tid < H_){
        float cval = 0.0f;
        #pragma unroll
        for (int ch = 0; ch < C_; ++ch){
            float ga = aggA[ch*BH_ + bb*H_ + tid];
            float gh = aggH[ch*BH_ + bb*H_ + tid];
            bool in = ch < cc;
            cval = fmaf(in ? ga : 1.0f, cval, in ? gh : 0.0f);
        }
        s_c[tid] = cval;
    }
    __syncthreads();

    // lane = t; each wave sums 32 cols; reads coalesced (64 lanes x 2B)
    {
        const unsigned short* src = pw_g + (size_t)bid*(T_*H_);
        int t = tid & 63, w4 = tid >> 6;
        float s = 0.0f;
        #pragma unroll
        for (int j = 0; j < 32; ++j){
            int col = w4*32 + j;
            s += s_c[col] * bf2f(src[col*T_ + t]);
        }
        s_part[w4*64 + t] = s;
    }
    __syncthreads();
    if (tid < 64){
        float s = s_part[tid] + s_part[64+tid] + s_part[128+tid] + s_part[192+tid];
        preds[(size_t)bb*L_ + t0g + tid] = s + sloc[(size_t)bid*T_ + tid] + bg[0];
    }
}

extern "C" void kernel_launch(void* const* d_in, const int* in_sizes, int n_in,
                              void* d_out, int out_size, void* d_ws, size_t ws_size,
                              hipStream_t stream){
    const float* x  = (const float*)d_in[0];
    const float* Wp = (const float*)d_in[1];
    const float* bp = (const float*)d_in[2];
    const float* Wz = (const float*)d_in[3];
    const float* bz = (const float*)d_in[4];
    const float* Wh = (const float*)d_in[5];
    const float* bh = (const float*)d_in[6];
    const float* Wg = (const float*)d_in[7];
    const float* bg = (const float*)d_in[8];
    float* preds = (float*)d_out;

    uint8_t* w8 = (uint8_t*)d_ws;
    unsigned short* WzT = (unsigned short*)(w8);
    unsigned short* WhT = (unsigned short*)(w8 + 32768);
    float* aggA = (float*)(w8 + 65536);                       // 2 MB
    float* aggH = (float*)(w8 + 65536 + 4u*BH_*C_);           // 2 MB
    float* sloc = (float*)(w8 + 65536 + 8u*BH_*C_);           // 1 MB
    unsigned short* pw_g = (unsigned short*)(w8 + 65536 + 12u*BH_*C_);  // 64 MB

    hipLaunchKernelGGL(prep_w, dim3(32), dim3(256), 0, stream, Wz, Wh, WzT, WhT);
    hipLaunchKernelGGL(gates_agg, dim3(B_*C_), dim3(256), 0, stream,
                       x, Wp, bp, bz, bh, Wg, WzT, WhT, aggA, aggH, sloc, pw_g);
    hipLaunchKernelGGL(apply2, dim3(B_*C_), dim3(256), 0, stream,
                       pw_g, aggA, aggH, sloc, bg, preds);
}